// Round 1
// baseline (1066.778 us; speedup 1.0000x reference)
//
#include <hip/hip_runtime.h>
#include <hip/hip_bf16.h>
#include <stdint.h>

#define SEQ 2048
#define DIMSZ 4096
#define QKVN 6144   // 4096 Q + 1024 K + 1024 V

typedef __attribute__((ext_vector_type(8))) __bf16 bf16x8;
typedef __attribute__((ext_vector_type(4))) float f32x4;

// async global->LDS, 16B per lane; dest = wave-uniform base + lane*16
static __device__ __forceinline__ void gld_lds16(const void* g, void* l) {
  __builtin_amdgcn_global_load_lds(
      (__attribute__((address_space(1))) void*)(g),
      (__attribute__((address_space(3))) void*)(l), 16, 0, 0);
}

// ---------------- fp32 -> bf16 conversion (vectorized) ----------------
__global__ __launch_bounds__(256) void k_cvt(const float* __restrict__ in,
                                             __bf16* __restrict__ out, long n) {
  long i = (long)blockIdx.x * 256 + threadIdx.x;
  long stride = (long)gridDim.x * 256;
  for (long e = i * 8; e < n; e += stride * 8) {
    float4 v0 = *(const float4*)(in + e);
    float4 v1 = *(const float4*)(in + e + 4);
    bf16x8 o;
    o[0] = (__bf16)v0.x; o[1] = (__bf16)v0.y; o[2] = (__bf16)v0.z; o[3] = (__bf16)v0.w;
    o[4] = (__bf16)v1.x; o[5] = (__bf16)v1.y; o[6] = (__bf16)v1.z; o[7] = (__bf16)v1.w;
    *(bf16x8*)(out + e) = o;
  }
}

// ---------------- bf16 GEMM, C = A * B^T  (A: MxK, B: NxK, both K-contig) --
// m97 structure: 128x128 tile, BK=32, 4 waves (2x2), global_load_lds staging.
template <typename OutT>
__global__ __launch_bounds__(256) void k_gemm_bt(const __bf16* __restrict__ A,
                                                 const __bf16* __restrict__ B,
                                                 OutT* __restrict__ C,
                                                 int M, int N, int K) {
  __shared__ __bf16 As[128 * 32];
  __shared__ __bf16 Bs[128 * 32];
  const int t = threadIdx.x;
  const int l = t & 63;
  const int w = t >> 6;
  const int wr = w >> 1, wc = w & 1;
  const int lr = l & 15, lg = l >> 4;
  const int bm = blockIdx.y, bn = blockIdx.x;
  const __bf16* Ab = A + (size_t)bm * 128 * K;
  const __bf16* Bb = B + (size_t)bn * 128 * K;
  f32x4 acc[4][4] = {};
  const int wbase = (t & ~63) * 8;

  for (int kt = 0; kt < K; kt += 32) {
    {
      const int e0 = t, e1 = t + 256;
      gld_lds16(Ab + (size_t)(e0 >> 2) * K + kt + (e0 & 3) * 8, &As[wbase]);
      gld_lds16(Ab + (size_t)(e1 >> 2) * K + kt + (e1 & 3) * 8, &As[2048 + wbase]);
      gld_lds16(Bb + (size_t)(e0 >> 2) * K + kt + (e0 & 3) * 8, &Bs[wbase]);
      gld_lds16(Bb + (size_t)(e1 >> 2) * K + kt + (e1 & 3) * 8, &Bs[2048 + wbase]);
    }
    __syncthreads();  // drains vmcnt (global_load_lds) + makes LDS visible
    bf16x8 a[4], b[4];
#pragma unroll
    for (int mi = 0; mi < 4; ++mi)
      a[mi] = *(const bf16x8*)&As[(wr * 64 + mi * 16 + lr) * 32 + lg * 8];
#pragma unroll
    for (int ni = 0; ni < 4; ++ni)
      b[ni] = *(const bf16x8*)&Bs[(wc * 64 + ni * 16 + lr) * 32 + lg * 8];
#pragma unroll
    for (int mi = 0; mi < 4; ++mi)
#pragma unroll
      for (int ni = 0; ni < 4; ++ni)
        acc[mi][ni] = __builtin_amdgcn_mfma_f32_16x16x32_bf16(a[mi], b[ni], acc[mi][ni], 0, 0, 0);
    __syncthreads();
  }

  const int row0 = bm * 128 + wr * 64;
  const int col0 = bn * 128 + wc * 64;
#pragma unroll
  for (int mi = 0; mi < 4; ++mi)
#pragma unroll
    for (int ni = 0; ni < 4; ++ni)
#pragma unroll
      for (int r = 0; r < 4; ++r)
        C[(size_t)(row0 + mi * 16 + lg * 4 + r) * N + (col0 + ni * 16 + lr)] =
            (OutT)acc[mi][ni][r];
}

// ---------------- fused RoPE + RMSNorm (in-place on Q and K regions) -------
// one wave per (row m, head); lane i owns the rotation pair (2i, 2i+1).
__global__ __launch_bounds__(256) void k_rope_norm(__bf16* __restrict__ qkv,
                                                   const float* __restrict__ cosT,
                                                   const float* __restrict__ sinT) {
  const int task = blockIdx.x * 4 + (threadIdx.x >> 6);
  const int l = threadIdx.x & 63;
  const int m = task / 40;          // row in [0, 4096)
  const int h = task - m * 40;      // 0..31 = Q heads, 32..39 = K heads
  const int s = m & (SEQ - 1);
  const bool isQ = h < 32;
  const int col = isQ ? h * 128 : 4096 + (h - 32) * 128;
  __bf16* p = qkv + (size_t)m * QKVN + col + l * 2;
  float e = (float)p[0], o = (float)p[1];
  float c = cosT[s * 64 + l], sn = sinT[s * 64 + l];
  float e2 = e * c - o * sn;
  float o2 = e * sn + o * c;
  float ss = e2 * e2 + o2 * o2;
#pragma unroll
  for (int off = 32; off > 0; off >>= 1) ss += __shfl_xor(ss, off);
  float r = rsqrtf(ss * (1.0f / 128.0f) + 1e-5f);
  if (isQ) r *= 0.08838834764831845f;  // fold 1/sqrt(HEAD_DIM) into Q
  p[0] = (__bf16)(e2 * r);
  p[1] = (__bf16)(o2 * r);
}

// ---------------- V transpose: qkv V region (b,s,g,d) -> vt (b,g,d,s) ------
__global__ __launch_bounds__(256) void k_transpose_v(const __bf16* __restrict__ qkv,
                                                     __bf16* __restrict__ vt) {
  __shared__ __bf16 tile[64][136];  // 136*2B = 272B row (16B-aligned)
  const int t = threadIdx.x;
  const int st = blockIdx.x, bg = blockIdx.y;
  const int b = bg >> 3, g = bg & 7;
  const int s0 = st * 64;
#pragma unroll
  for (int p = 0; p < 4; ++p) {
    int row = p * 16 + (t >> 4);
    int co = (t & 15) * 8;
    *(bf16x8*)&tile[row][co] =
        *(const bf16x8*)&qkv[(size_t)(b * SEQ + s0 + row) * QKVN + 5120 + g * 128 + co];
  }
  __syncthreads();
#pragma unroll
  for (int p = 0; p < 4; ++p) {
    int d = p * 32 + (t >> 3);
    int so = (t & 7) * 8;
    bf16x8 v;
#pragma unroll
    for (int j = 0; j < 8; ++j) v[j] = tile[so + j][d];
    *(bf16x8*)&vt[((size_t)bg * 128 + d) * SEQ + s0 + so] = v;
  }
}

// ---------------- causal flash attention (GQA) ------------------------------
// block = 4 waves; wave owns 16 q-rows; KVBLK=64 staged in LDS.
__global__ __launch_bounds__(256) void k_flash(const __bf16* __restrict__ qkv,
                                               const __bf16* __restrict__ vt,
                                               __bf16* __restrict__ attno) {
  __shared__ __bf16 Ks[64 * 128];   // [kv][d]
  __shared__ __bf16 Vs[128 * 64];   // [d][kv]
  __shared__ __bf16 Ps[4][16 * 64]; // per-wave P tile [q][kv]
  const int t = threadIdx.x, w = t >> 6, l = t & 63;
  const int lr = l & 15, lg = l >> 4;
  const int qt = blockIdx.x;        // q tile (64 rows)
  const int bh = blockIdx.y;        // b*32 + h
  const int b = bh >> 5, h = bh & 31, g = h >> 2;

  // Q fragments hoisted to registers (scale already folded in)
  const __bf16* Qb = qkv + (size_t)(b * SEQ + qt * 64 + w * 16 + lr) * QKVN + h * 128;
  bf16x8 qf[4];
#pragma unroll
  for (int kk = 0; kk < 4; ++kk) qf[kk] = *(const bf16x8*)&Qb[kk * 32 + lg * 8];

  f32x4 oacc[8] = {};
  float mrow[4], lsum[4];
#pragma unroll
  for (int r = 0; r < 4; ++r) { mrow[r] = -1e30f; lsum[r] = 0.f; }

  const __bf16* Kb = qkv + 4096 + (size_t)(b * SEQ) * QKVN + g * 128;
  const __bf16* Vtb = vt + ((size_t)(b * 8 + g)) * 128 * SEQ;
  const int wbase = (t & ~63) * 8;

  const int ntiles = qt + 1;  // causal: only tiles at/below the diagonal
  for (int kt = 0; kt < ntiles; ++kt) {
    const int kv0 = kt * 64;
#pragma unroll
    for (int i = 0; i < 4; ++i) {
      int e = i * 256 + t;
      gld_lds16(Kb + (size_t)(kv0 + (e >> 4)) * QKVN + (e & 15) * 8, &Ks[i * 2048 + wbase]);
    }
#pragma unroll
    for (int i = 0; i < 4; ++i) {
      int e = i * 256 + t;
      gld_lds16(Vtb + (size_t)(e >> 3) * SEQ + kv0 + (e & 7) * 8, &Vs[i * 2048 + wbase]);
    }
    __syncthreads();

    // S = Q K^T
    f32x4 sc[4] = {};
#pragma unroll
    for (int kk = 0; kk < 4; ++kk)
#pragma unroll
      for (int n = 0; n < 4; ++n) {
        bf16x8 kf = *(const bf16x8*)&Ks[(n * 16 + lr) * 128 + kk * 32 + lg * 8];
        sc[n] = __builtin_amdgcn_mfma_f32_16x16x32_bf16(qf[kk], kf, sc[n], 0, 0, 0);
      }

    if (kt == qt) {  // diagonal tile: causal mask
#pragma unroll
      for (int n = 0; n < 4; ++n)
#pragma unroll
        for (int r = 0; r < 4; ++r)
          if (n * 16 + lr > w * 16 + lg * 4 + r) sc[n][r] = -1e30f;
    }

    // online softmax (row = lg*4 + r, 16 lanes of the group hold the cols)
#pragma unroll
    for (int r = 0; r < 4; ++r) {
      float pm = fmaxf(fmaxf(sc[0][r], sc[1][r]), fmaxf(sc[2][r], sc[3][r]));
#pragma unroll
      for (int off = 8; off > 0; off >>= 1) pm = fmaxf(pm, __shfl_xor(pm, off));
      float mn = fmaxf(mrow[r], pm);
      float corr = __expf(mrow[r] - mn);
      mrow[r] = mn;
      float ps = 0.f;
#pragma unroll
      for (int n = 0; n < 4; ++n) { sc[n][r] = __expf(sc[n][r] - mn); ps += sc[n][r]; }
#pragma unroll
      for (int off = 8; off > 0; off >>= 1) ps += __shfl_xor(ps, off);
      lsum[r] = lsum[r] * corr + ps;
#pragma unroll
      for (int dn = 0; dn < 8; ++dn) oacc[dn][r] *= corr;
    }

    // P -> LDS (re-layout for MFMA A-operand)
#pragma unroll
    for (int n = 0; n < 4; ++n)
#pragma unroll
      for (int r = 0; r < 4; ++r)
        Ps[w][(lg * 4 + r) * 64 + n * 16 + lr] = (__bf16)sc[n][r];

    // O += P V
#pragma unroll
    for (int ks = 0; ks < 2; ++ks) {
      bf16x8 pf = *(const bf16x8*)&Ps[w][lr * 64 + ks * 32 + lg * 8];
#pragma unroll
      for (int dn = 0; dn < 8; ++dn) {
        bf16x8 vf = *(const bf16x8*)&Vs[(dn * 16 + lr) * 64 + ks * 32 + lg * 8];
        oacc[dn] = __builtin_amdgcn_mfma_f32_16x16x32_bf16(pf, vf, oacc[dn], 0, 0, 0);
      }
    }
    __syncthreads();  // protect Ks/Vs before next tile's staging
  }

  __bf16* Ob = attno + (size_t)(b * SEQ + qt * 64 + w * 16) * DIMSZ + h * 128;
#pragma unroll
  for (int dn = 0; dn < 8; ++dn)
#pragma unroll
    for (int r = 0; r < 4; ++r)
      Ob[(size_t)(lg * 4 + r) * DIMSZ + dn * 16 + lr] = (__bf16)(oacc[dn][r] / lsum[r]);
}

// ---------------- host launcher --------------------------------------------
extern "C" void kernel_launch(void* const* d_in, const int* in_sizes, int n_in,
                              void* d_out, int out_size, void* d_ws, size_t ws_size,
                              hipStream_t stream) {
  const float* x    = (const float*)d_in[0];
  const float* wq   = (const float*)d_in[1];
  const float* wk   = (const float*)d_in[2];
  const float* wv   = (const float*)d_in[3];
  const float* wo   = (const float*)d_in[4];
  const float* cosT = (const float*)d_in[5];
  const float* sinT = (const float*)d_in[6];
  // d_in[7] (mask) implemented as causal; d_in[8] (start_pos) == 0.

  char* ws = (char*)d_ws;
  __bf16* xb    = (__bf16*)(ws);                    // 4096x4096        (32 MiB)
  __bf16* wqkvb = (__bf16*)(ws + 33554432);         // 6144x4096        (48 MiB)
  __bf16* qkvb  = (__bf16*)(ws + 83886080);         // 4096x6144        (48 MiB)
  __bf16* wob   = (__bf16*)(ws + 134217728);        // 4096x4096        (32 MiB)
  __bf16* vt    = (__bf16*)(ws + 167772160);        // 16x128x2048      ( 8 MiB)
  __bf16* attno = (__bf16*)(ws + 176160768);        // 4096x4096        (32 MiB)
  float* out = (float*)d_out;

  // fp32 -> bf16 conversions (wq/wk/wv concatenated into one 6144x4096 weight)
  k_cvt<<<8192, 256, 0, stream>>>(x, xb, 16777216L);
  k_cvt<<<8192, 256, 0, stream>>>(wq, wqkvb, 16777216L);
  k_cvt<<<2048, 256, 0, stream>>>(wk, wqkvb + 16777216, 4194304L);
  k_cvt<<<2048, 256, 0, stream>>>(wv, wqkvb + 20971520, 4194304L);
  k_cvt<<<8192, 256, 0, stream>>>(wo, wob, 16777216L);

  // QKV projection
  k_gemm_bt<__bf16><<<dim3(48, 32), 256, 0, stream>>>(xb, wqkvb, qkvb, 4096, QKVN, 4096);
  // RoPE + RMSNorm on Q,K (in place), attention scale folded into Q
  k_rope_norm<<<40960, 256, 0, stream>>>(qkvb, cosT, sinT);
  // V -> V^T for contiguous PV operand reads
  k_transpose_v<<<dim3(32, 16), 256, 0, stream>>>(qkvb, vt);
  // causal GQA flash attention
  k_flash<<<dim3(32, 64), 256, 0, stream>>>(qkvb, vt, attno);
  // output projection, fp32 straight into d_out
  k_gemm_bt<float><<<dim3(32, 32), 256, 0, stream>>>(attno, wob, out, 4096, DIMSZ, 4096);
}

// Round 2
// 739.417 us; speedup vs baseline: 1.4427x; 1.4427x over previous
//
#include <hip/hip_runtime.h>
#include <hip/hip_bf16.h>
#include <stdint.h>

#define SEQ 2048
#define DIMSZ 4096
#define QKVN 6144   // 4096 Q + 1024 K + 1024 V

typedef __attribute__((ext_vector_type(8))) __bf16 bf16x8;
typedef __attribute__((ext_vector_type(4))) float f32x4;

// async global->LDS, 16B per lane; dest = wave-uniform base + lane*16
static __device__ __forceinline__ void gld_lds16(const void* g, void* l) {
  __builtin_amdgcn_global_load_lds(
      (__attribute__((address_space(1))) void*)(g),
      (__attribute__((address_space(3))) void*)(l), 16, 0, 0);
}

// ---------------- fp32 -> bf16 conversion (vectorized) ----------------
__global__ __launch_bounds__(256) void k_cvt(const float* __restrict__ in,
                                             __bf16* __restrict__ out, long n) {
  long i = (long)blockIdx.x * 256 + threadIdx.x;
  long stride = (long)gridDim.x * 256;
  for (long e = i * 8; e < n; e += stride * 8) {
    float4 v0 = *(const float4*)(in + e);
    float4 v1 = *(const float4*)(in + e + 4);
    bf16x8 o;
    o[0] = (__bf16)v0.x; o[1] = (__bf16)v0.y; o[2] = (__bf16)v0.z; o[3] = (__bf16)v0.w;
    o[4] = (__bf16)v1.x; o[5] = (__bf16)v1.y; o[6] = (__bf16)v1.z; o[7] = (__bf16)v1.w;
    *(bf16x8*)(out + e) = o;
  }
}

// ---------------- bf16 GEMM, C = A * B^T  (A: MxK, B: NxK, both K-contig) --
// m97 structure: 128x128 tile, BK=32, 4 waves (2x2), global_load_lds staging.
template <typename OutT>
__global__ __launch_bounds__(256) void k_gemm_bt(const __bf16* __restrict__ A,
                                                 const __bf16* __restrict__ B,
                                                 OutT* __restrict__ C,
                                                 int M, int N, int K) {
  __shared__ __bf16 As[128 * 32];
  __shared__ __bf16 Bs[128 * 32];
  const int t = threadIdx.x;
  const int l = t & 63;
  const int w = t >> 6;
  const int wr = w >> 1, wc = w & 1;
  const int lr = l & 15, lg = l >> 4;
  const int bm = blockIdx.y, bn = blockIdx.x;
  const __bf16* Ab = A + (size_t)bm * 128 * K;
  const __bf16* Bb = B + (size_t)bn * 128 * K;
  f32x4 acc[4][4] = {};
  const int wbase = (t & ~63) * 8;

  for (int kt = 0; kt < K; kt += 32) {
    {
      const int e0 = t, e1 = t + 256;
      gld_lds16(Ab + (size_t)(e0 >> 2) * K + kt + (e0 & 3) * 8, &As[wbase]);
      gld_lds16(Ab + (size_t)(e1 >> 2) * K + kt + (e1 & 3) * 8, &As[2048 + wbase]);
      gld_lds16(Bb + (size_t)(e0 >> 2) * K + kt + (e0 & 3) * 8, &Bs[wbase]);
      gld_lds16(Bb + (size_t)(e1 >> 2) * K + kt + (e1 & 3) * 8, &Bs[2048 + wbase]);
    }
    __syncthreads();  // drains vmcnt (global_load_lds) + makes LDS visible
    bf16x8 a[4], b[4];
#pragma unroll
    for (int mi = 0; mi < 4; ++mi)
      a[mi] = *(const bf16x8*)&As[(wr * 64 + mi * 16 + lr) * 32 + lg * 8];
#pragma unroll
    for (int ni = 0; ni < 4; ++ni)
      b[ni] = *(const bf16x8*)&Bs[(wc * 64 + ni * 16 + lr) * 32 + lg * 8];
#pragma unroll
    for (int mi = 0; mi < 4; ++mi)
#pragma unroll
      for (int ni = 0; ni < 4; ++ni)
        acc[mi][ni] = __builtin_amdgcn_mfma_f32_16x16x32_bf16(a[mi], b[ni], acc[mi][ni], 0, 0, 0);
    __syncthreads();
  }

  const int row0 = bm * 128 + wr * 64;
  const int col0 = bn * 128 + wc * 64;
#pragma unroll
  for (int mi = 0; mi < 4; ++mi)
#pragma unroll
    for (int ni = 0; ni < 4; ++ni)
#pragma unroll
      for (int r = 0; r < 4; ++r)
        C[(size_t)(row0 + mi * 16 + lg * 4 + r) * N + (col0 + ni * 16 + lr)] =
            (OutT)acc[mi][ni][r];
}

// ---------------- fused RoPE + RMSNorm (in-place on Q and K regions) -------
__global__ __launch_bounds__(256) void k_rope_norm(__bf16* __restrict__ qkv,
                                                   const float* __restrict__ cosT,
                                                   const float* __restrict__ sinT) {
  const int task = blockIdx.x * 4 + (threadIdx.x >> 6);
  const int l = threadIdx.x & 63;
  const int m = task / 40;          // row in [0, 4096)
  const int h = task - m * 40;      // 0..31 = Q heads, 32..39 = K heads
  const int s = m & (SEQ - 1);
  const bool isQ = h < 32;
  const int col = isQ ? h * 128 : 4096 + (h - 32) * 128;
  __bf16* p = qkv + (size_t)m * QKVN + col + l * 2;
  float e = (float)p[0], o = (float)p[1];
  float c = cosT[s * 64 + l], sn = sinT[s * 64 + l];
  float e2 = e * c - o * sn;
  float o2 = e * sn + o * c;
  float ss = e2 * e2 + o2 * o2;
#pragma unroll
  for (int off = 32; off > 0; off >>= 1) ss += __shfl_xor(ss, off);
  float r = rsqrtf(ss * (1.0f / 128.0f) + 1e-5f);
  if (isQ) r *= 0.08838834764831845f;  // fold 1/sqrt(HEAD_DIM) into Q
  p[0] = (__bf16)(e2 * r);
  p[1] = (__bf16)(o2 * r);
}

// ---------------- V transpose: qkv V region (b,s,g,d) -> vt (b,g,d,s) ------
__global__ __launch_bounds__(256) void k_transpose_v(const __bf16* __restrict__ qkv,
                                                     __bf16* __restrict__ vt) {
  __shared__ __bf16 tile[64][136];  // padded row, no bank conflicts
  const int t = threadIdx.x;
  const int st = blockIdx.x, bg = blockIdx.y;
  const int b = bg >> 3, g = bg & 7;
  const int s0 = st * 64;
#pragma unroll
  for (int p = 0; p < 4; ++p) {
    int row = p * 16 + (t >> 4);
    int co = (t & 15) * 8;
    *(bf16x8*)&tile[row][co] =
        *(const bf16x8*)&qkv[(size_t)(b * SEQ + s0 + row) * QKVN + 5120 + g * 128 + co];
  }
  __syncthreads();
#pragma unroll
  for (int p = 0; p < 4; ++p) {
    int d = p * 32 + (t >> 3);
    int so = (t & 7) * 8;
    bf16x8 v;
#pragma unroll
    for (int j = 0; j < 8; ++j) v[j] = tile[so + j][d];
    *(bf16x8*)&vt[((size_t)bg * 128 + d) * SEQ + s0 + so] = v;
  }
}

// ---------------- causal flash attention (GQA) ------------------------------
// 4 waves; wave owns 16 q-rows; KVBLK=64. Paired q-tiles (qt, 31-qt) for
// balance: grid.x=16, every block does exactly 33 kv-iters; 1024 blocks =
// 4/CU (the LDS limit) -> all co-resident, no tail.
// All LDS buffers XOR-swizzled at 16B-chunk granularity (chunk ^= row&7);
// global_load_lds writes linearly, so staging pre-swizzles the GLOBAL source
// address (rule: same involution on source-permute and read).
__global__ __launch_bounds__(256) void k_flash(const __bf16* __restrict__ qkv,
                                               const __bf16* __restrict__ vt,
                                               __bf16* __restrict__ attno) {
  __shared__ __bf16 Ks[64 * 128];   // [kv][d], swizzled
  __shared__ __bf16 Vs[128 * 64];   // [d][kv], swizzled
  __shared__ __bf16 Ps[4][16 * 64]; // per-wave [q][kv], swizzled
  const int t = threadIdx.x, w = t >> 6, l = t & 63;
  const int lr = l & 15, lg = l >> 4;
  const int bh = blockIdx.y;        // b*32 + h
  const int b = bh >> 5, h = bh & 31, g = h >> 2;
  const int qt0 = blockIdx.x, qt1 = 31 - (int)blockIdx.x;

  const __bf16* Kb = qkv + 4096 + (size_t)(b * SEQ) * QKVN + g * 128;
  const __bf16* Vtb = vt + ((size_t)(b * 8 + g)) * 128 * SEQ;
  const int wbase = (t & ~63) * 8;
  const int sw = lr & 7;            // read-side XOR (row&7 == lr&7 everywhere)

  for (int pass = 0; pass < 2; ++pass) {
    const int qt = (pass == 0) ? qt0 : qt1;

    const __bf16* Qb = qkv + (size_t)(b * SEQ + qt * 64 + w * 16 + lr) * QKVN + h * 128;
    bf16x8 qf[4];
#pragma unroll
    for (int kk = 0; kk < 4; ++kk) qf[kk] = *(const bf16x8*)&Qb[kk * 32 + lg * 8];

    f32x4 oacc[8] = {};
    float mrow[4], lsum[4];
#pragma unroll
    for (int r = 0; r < 4; ++r) { mrow[r] = -1e30f; lsum[r] = 0.f; }

    for (int kt = 0; kt <= qt; ++kt) {
      const int kv0 = kt * 64;
      // stage K: dest chunk q of row holds global chunk q^(row&7)
#pragma unroll
      for (int i = 0; i < 4; ++i) {
        int e = i * 256 + t;
        gld_lds16(Kb + (size_t)(kv0 + (e >> 4)) * QKVN + ((e & 15) ^ ((e >> 4) & 7)) * 8,
                  &Ks[i * 2048 + wbase]);
      }
#pragma unroll
      for (int i = 0; i < 4; ++i) {
        int e = i * 256 + t;
        gld_lds16(Vtb + (size_t)(e >> 3) * SEQ + kv0 + (((e & 7) ^ ((e >> 3) & 7))) * 8,
                  &Vs[i * 2048 + wbase]);
      }
      __syncthreads();

      // S = Q K^T   (Ks row = n*16+lr, chunk kk*4+lg, XOR with lr&7)
      f32x4 sc[4] = {};
#pragma unroll
      for (int kk = 0; kk < 4; ++kk)
#pragma unroll
        for (int n = 0; n < 4; ++n) {
          bf16x8 kf = *(const bf16x8*)&Ks[(n * 16 + lr) * 128 + ((kk * 4 + lg) ^ sw) * 8];
          sc[n] = __builtin_amdgcn_mfma_f32_16x16x32_bf16(qf[kk], kf, sc[n], 0, 0, 0);
        }

      if (kt == qt) {  // diagonal tile: causal mask
#pragma unroll
        for (int n = 0; n < 4; ++n)
#pragma unroll
          for (int r = 0; r < 4; ++r)
            if (n * 16 + lr > w * 16 + lg * 4 + r) sc[n][r] = -1e30f;
      }

      // online softmax (row = lg*4 + r; 16 lanes hold the cols)
#pragma unroll
      for (int r = 0; r < 4; ++r) {
        float pm = fmaxf(fmaxf(sc[0][r], sc[1][r]), fmaxf(sc[2][r], sc[3][r]));
#pragma unroll
        for (int off = 8; off > 0; off >>= 1) pm = fmaxf(pm, __shfl_xor(pm, off));
        float mn = fmaxf(mrow[r], pm);
        float corr = __expf(mrow[r] - mn);
        mrow[r] = mn;
        float ps = 0.f;
#pragma unroll
        for (int n = 0; n < 4; ++n) { sc[n][r] = __expf(sc[n][r] - mn); ps += sc[n][r]; }
#pragma unroll
        for (int off = 8; off > 0; off >>= 1) ps += __shfl_xor(ps, off);
        lsum[r] = lsum[r] * corr + ps;
#pragma unroll
        for (int dn = 0; dn < 8; ++dn) oacc[dn][r] *= corr;
      }

      // P -> LDS (swizzled): logical (row, col=n*16+lr) -> chunk (n*2+(lr>>3))^(row&7)
#pragma unroll
      for (int n = 0; n < 4; ++n)
#pragma unroll
        for (int r = 0; r < 4; ++r) {
          int row = lg * 4 + r;
          Ps[w][row * 64 + (((n * 2 + (lr >> 3)) ^ (row & 7)) * 8) + (lr & 7)] = (__bf16)sc[n][r];
        }

      // O += P V   (Ps row = lr, chunk ks*4+lg; Vs row = dn*16+lr, chunk ks*4+lg)
#pragma unroll
      for (int ks = 0; ks < 2; ++ks) {
        bf16x8 pf = *(const bf16x8*)&Ps[w][lr * 64 + ((ks * 4 + lg) ^ sw) * 8];
#pragma unroll
        for (int dn = 0; dn < 8; ++dn) {
          bf16x8 vf = *(const bf16x8*)&Vs[(dn * 16 + lr) * 64 + ((ks * 4 + lg) ^ sw) * 8];
          oacc[dn] = __builtin_amdgcn_mfma_f32_16x16x32_bf16(pf, vf, oacc[dn], 0, 0, 0);
        }
      }
      __syncthreads();  // protect Ks/Vs before next tile's staging
    }

    __bf16* Ob = attno + (size_t)(b * SEQ + qt * 64 + w * 16) * DIMSZ + h * 128;
#pragma unroll
    for (int dn = 0; dn < 8; ++dn)
#pragma unroll
      for (int r = 0; r < 4; ++r)
        Ob[(size_t)(lg * 4 + r) * DIMSZ + dn * 16 + lr] = (__bf16)(oacc[dn][r] / lsum[r]);
  }
}

// ---------------- host launcher --------------------------------------------
extern "C" void kernel_launch(void* const* d_in, const int* in_sizes, int n_in,
                              void* d_out, int out_size, void* d_ws, size_t ws_size,
                              hipStream_t stream) {
  const float* x    = (const float*)d_in[0];
  const float* wq   = (const float*)d_in[1];
  const float* wk   = (const float*)d_in[2];
  const float* wv   = (const float*)d_in[3];
  const float* wo   = (const float*)d_in[4];
  const float* cosT = (const float*)d_in[5];
  const float* sinT = (const float*)d_in[6];
  // d_in[7] (mask) implemented as causal; d_in[8] (start_pos) == 0.

  char* ws = (char*)d_ws;
  __bf16* xb    = (__bf16*)(ws);                    // 4096x4096        (32 MiB)
  __bf16* wqkvb = (__bf16*)(ws + 33554432);         // 6144x4096        (48 MiB)
  __bf16* qkvb  = (__bf16*)(ws + 83886080);         // 4096x6144        (48 MiB)
  __bf16* wob   = (__bf16*)(ws + 134217728);        // 4096x4096        (32 MiB)
  __bf16* vt    = (__bf16*)(ws + 167772160);        // 16x128x2048      ( 8 MiB)
  __bf16* attno = (__bf16*)(ws + 176160768);        // 4096x4096        (32 MiB)
  float* out = (float*)d_out;

  // fp32 -> bf16 conversions (wq/wk/wv concatenated into one 6144x4096 weight)
  k_cvt<<<8192, 256, 0, stream>>>(x, xb, 16777216L);
  k_cvt<<<8192, 256, 0, stream>>>(wq, wqkvb, 16777216L);
  k_cvt<<<2048, 256, 0, stream>>>(wk, wqkvb + 16777216, 4194304L);
  k_cvt<<<2048, 256, 0, stream>>>(wv, wqkvb + 20971520, 4194304L);
  k_cvt<<<8192, 256, 0, stream>>>(wo, wob, 16777216L);

  // QKV projection
  k_gemm_bt<__bf16><<<dim3(48, 32), 256, 0, stream>>>(xb, wqkvb, qkvb, 4096, QKVN, 4096);
  // RoPE + RMSNorm on Q,K (in place), attention scale folded into Q
  k_rope_norm<<<40960, 256, 0, stream>>>(qkvb, cosT, sinT);
  // V -> V^T for contiguous PV operand reads
  k_transpose_v<<<dim3(32, 16), 256, 0, stream>>>(qkvb, vt);
  // causal GQA flash attention (paired q-tiles for balance)
  k_flash<<<dim3(16, 64), 256, 0, stream>>>(qkvb, vt, attno);
  // output projection, fp32 straight into d_out
  k_gemm_bt<float><<<dim3(32, 32), 256, 0, stream>>>(attno, wob, out, 4096, DIMSZ, 4096);
}